// Round 4
// baseline (554.117 us; speedup 1.0000x reference)
//
#include <hip/hip_runtime.h>
#include <hip/hip_bf16.h>
#include <stdint.h>

// Problem constants
#define B_    4
#define L_    2048
#define INK   256
#define HID   1024
#define NH    8
#define DH    128
#define OUTF  256

typedef __bf16 v8bf __attribute__((ext_vector_type(8)));
typedef float  v4f  __attribute__((ext_vector_type(4)));

#define MFMA(a,b,c) __builtin_amdgcn_mfma_f32_16x16x32_bf16((a),(b),(c),0,0,0)

__device__ __forceinline__ void gl_lds16(const void* gsrc, void* ldsbase) {
  __builtin_amdgcn_global_load_lds(
      (const __attribute__((address_space(1))) unsigned int*)(uintptr_t)gsrc,
      (__attribute__((address_space(3))) unsigned int*)(uint32_t)(uintptr_t)ldsbase,
      16, 0, 0);
}
__device__ __forceinline__ void wait_vm0()  { asm volatile("s_waitcnt vmcnt(0)" ::: "memory"); }
__device__ __forceinline__ void wait_vm8()  { asm volatile("s_waitcnt vmcnt(8)" ::: "memory"); }
__device__ __forceinline__ void barrier_lgkm() {
  asm volatile("s_waitcnt lgkmcnt(0)\n\ts_barrier" ::: "memory");
}

__device__ __forceinline__ unsigned short bfbits(float f) {
  __bf16 h = (__bf16)f;
  return __builtin_bit_cast(unsigned short, h);
}
__device__ __forceinline__ unsigned pack2(float a, float b) {
  return (unsigned)bfbits(a) | ((unsigned)bfbits(b) << 16);
}

// ---------------------------------------------------------------------------
// fp32 -> bf16 bulk convert (KEY, QUERY, VALUE, W_w, Wv_w)
// ---------------------------------------------------------------------------
struct ConvArgs {
  const float* src[5];
  __bf16* dst[5];
  int n[5];
};
__global__ __launch_bounds__(256)
void convert_kernel(ConvArgs a) {
  const int r = blockIdx.y;
  const int i = (blockIdx.x * 256 + threadIdx.x) * 4;
  if (i >= a.n[r]) return;
  const float4 v = *(const float4*)(a.src[r] + i);
  uint2 w;
  w.x = pack2(v.x, v.y);
  w.y = pack2(v.z, v.w);
  *reinterpret_cast<uint2*>(a.dst[r] + i) = w;
}

// Wo[o][dd*8+h] fp32  ->  Wop[o][h*128+dd] bf16   (head-major permute)
__global__ __launch_bounds__(256)
void wo_perm_kernel(const float* __restrict__ Wo, __bf16* __restrict__ Wop) {
  const int o = blockIdx.x;
  const int hidp = threadIdx.x * 4;
  const int h = hidp >> 7, dd = hidp & 127;
  const float* src = Wo + (size_t)o * HID;
  const float v0 = src[(dd + 0) * 8 + h];
  const float v1 = src[(dd + 1) * 8 + h];
  const float v2 = src[(dd + 2) * 8 + h];
  const float v3 = src[(dd + 3) * 8 + h];
  uint2 w;
  w.x = pack2(v0, v1);
  w.y = pack2(v2, v3);
  *reinterpret_cast<uint2*>(Wop + (size_t)o * HID + hidp) = w;
}

// ---------------------------------------------------------------------------
// Projection (bf16 NT GEMM, K=256)
// MODE 0: out[((b*8+h)*L+i)*128+dd]   MODE 1: out[((b*8+h)*128+dd)*L+i]
// ---------------------------------------------------------------------------
template<int MODE>
__global__ __launch_bounds__(256, 2)
void proj_kernel(const __bf16* __restrict__ X, const __bf16* __restrict__ W,
                 const float* __restrict__ bias, __bf16* __restrict__ out)
{
  __shared__ __bf16 sA[2][128 * 64];
  __shared__ __bf16 sB[2][128 * 64];
  const int tid  = threadIdx.x;
  const int lane = tid & 63;
  const int wid  = tid >> 6;
  const int l15  = lane & 15;
  const int q    = lane >> 4;
  const int mblk = blockIdx.x * 128;
  const int nblk = blockIdx.y * 128;

  v4f acc[4][4];
  const v4f vz = {0.f, 0.f, 0.f, 0.f};
#pragma unroll
  for (int i = 0; i < 4; i++)
#pragma unroll
    for (int j = 0; j < 4; j++) acc[i][j] = vz;

  const char* Ab = (const char*)X + (size_t)mblk * 512;
  const char* Bb = (const char*)W + (size_t)nblk * 512;

  auto stage = [&](int p, int c) {
    const int koff = c * 128;
#pragma unroll
    for (int j = 0; j < 4; j++) {
      const int slot = j * 256 + tid;
      const int row = slot >> 3, g = slot & 7;
      gl_lds16(Ab + (size_t)row * 512 + koff + ((g ^ (row & 7)) << 4),
               &sA[p][(j * 256 + wid * 64) * 8]);
    }
#pragma unroll
    for (int j = 0; j < 4; j++) {
      const int slot = j * 256 + tid;
      const int row = slot >> 3, g = slot & 7;
      gl_lds16(Bb + (size_t)row * 512 + koff + ((g ^ (row & 7)) << 4),
               &sB[p][(j * 256 + wid * 64) * 8]);
    }
  };

  stage(0, 0);
  __syncthreads();
#pragma unroll
  for (int c = 0; c < 4; c++) {
    const int p = c & 1;
    if (c + 1 < 4) stage(1 - p, c + 1);
#pragma unroll
    for (int s = 0; s < 2; s++) {
      v8bf a[4], b[4];
#pragma unroll
      for (int t = 0; t < 4; t++) {
        const int row = (wid & 1) * 64 + t * 16 + l15;
        a[t] = *(const v8bf*)&sA[p][(row << 6) + (((s * 4 + q) ^ (row & 7)) << 3)];
      }
#pragma unroll
      for (int t = 0; t < 4; t++) {
        const int row = (wid >> 1) * 64 + t * 16 + l15;
        b[t] = *(const v8bf*)&sB[p][(row << 6) + (((s * 4 + q) ^ (row & 7)) << 3)];
      }
#pragma unroll
      for (int tm = 0; tm < 4; tm++)
#pragma unroll
        for (int tn = 0; tn < 4; tn++)
          acc[tm][tn] = MFMA(a[tm], b[tn], acc[tm][tn]);
    }
    __syncthreads();
  }

#pragma unroll
  for (int tn = 0; tn < 4; tn++) {
    const int n = nblk + (wid >> 1) * 64 + tn * 16 + l15;
    const float bv = bias[n];
    const int h = n & 7;
    const int dd = n >> 3;
#pragma unroll
    for (int tm = 0; tm < 4; tm++)
#pragma unroll
      for (int r = 0; r < 4; r++) {
        const int m = mblk + (wid & 1) * 64 + tm * 16 + q * 4 + r;
        const int b = m >> 11;
        const int i = m & (L_ - 1);
        const float v = acc[tm][tn][r] + bv;
        size_t idx;
        if (MODE == 0) idx = ((size_t)(b * NH + h) * L_ + i) * DH + dd;
        else           idx = ((size_t)(b * NH + h) * DH + dd) * L_ + i;
        out[idx] = (__bf16)v;
      }
  }
}

// ---------------------------------------------------------------------------
// FUSED attention v2: QK^T + head-softmax + PV. P never leaves LDS.
// Block = 512 thr = 8 waves; wave h owns head h; 32 k-cols; 64 i-tiles of 32.
// K fragments: DIRECT global->VGPR (coalesced 64B-line reads, no LDS).
// V: global_load_lds, granule-major layout sV[p][h][ii][dd][16B] -> va reads
//    are 16B-stride rows = conflict-free. Double-buffered prefetch.
// sP: row stride 80 B (16B-aligned, bank-decorrelated).
// Grid (64 ktiles, 4 batches). LDS: 2*64KB (sV) + 20KB (sP) = 151552 B.
// ---------------------------------------------------------------------------
__global__ __launch_bounds__(512, 2)
void fused_attn_kernel(const __bf16* __restrict__ Kp,
                       const __bf16* __restrict__ Qp,
                       const __bf16* __restrict__ Vpt,
                       __bf16* __restrict__ Hd)
{
  extern __shared__ char smem[];
  char* sV = smem;                    // 2 x 64 KB
  char* sP = smem + 131072;           // 8 heads x 32 k x 80 B = 20480 B

  const int tid  = threadIdx.x;
  const int lane = tid & 63;
  const int h    = tid >> 6;          // wave id == head
  const int l15  = lane & 15;
  const int q    = lane >> 4;
  const int k0   = blockIdx.x * 32;
  const int b    = blockIdx.y;

  const char* KpH = (const char*)Kp  + (size_t)(b * NH + h) * L_ * DH * 2;
  const char* QpH = (const char*)Qp  + (size_t)(b * NH + h) * L_ * DH * 2;
  const char* VpH = (const char*)Vpt + (size_t)(b * NH + h) * DH * L_ * 2;
  char* sPh = sP + h * 2560;

  // stage V tile (i0..i0+31) for this head into buffer p.
  // LDS layout: offset = ii*2048 + dd*16  (ii = i-granule of 8, dd = 0..127)
  auto stage_V = [&](int p, int i0) {
    char* sVp = sV + p * 65536 + h * 8192;
#pragma unroll
    for (int j = 0; j < 8; j++) {
      const int slot = j * 64 + lane;
      const int dd = slot & 127;
      const int ii = slot >> 7;
      gl_lds16(VpH + (size_t)dd * 4096 + (size_t)i0 * 2 + ii * 16,
               sVp + j * 1024);
    }
  };

  stage_V(0, 0);

  // Q fragments, in registers for the whole kernel: [ksub 2][dchunk 4]
  v8bf qf[2][4];
#pragma unroll
  for (int n = 0; n < 2; n++)
#pragma unroll
    for (int c = 0; c < 4; c++)
      qf[n][c] = *(const v8bf*)(QpH + (size_t)(k0 + n * 16 + l15) * 256 + c * 64 + q * 16);

  v4f cacc[8][2];
  const v4f vz = {0.f, 0.f, 0.f, 0.f};
#pragma unroll
  for (int t = 0; t < 8; t++)
#pragma unroll
    for (int n = 0; n < 2; n++) cacc[t][n] = vz;

  const float c2 = 0.12751744f;  // log2(e)/sqrt(128)
  const int ip = tid & 15;        // normalize-phase: i-pair index
  const int kk = tid >> 4;        // and k (0..31)

  for (int it = 0; it < 64; ++it) {
    const int i0 = it * 32;
    const int p = it & 1;

    // 1. K fragments for this tile: direct global loads (each reads 16 full
    //    64B lines; rows are i, cols are one 64B d-granule).
    v8bf ka[2][4];
#pragma unroll
    for (int si = 0; si < 2; si++)
#pragma unroll
      for (int c = 0; c < 4; c++)
        ka[si][c] = *(const v8bf*)(KpH + (size_t)(i0 + si * 16 + l15) * 256 + (c * 4 + q) * 16);

    // 2. prefetch next V tile into the other buffer
    if (it + 1 < 64) {
      stage_V(1 - p, i0 + 32);
      wait_vm8();   // drains V(it) + ka; leaves V(it+1) in flight
    } else {
      wait_vm0();
    }

    // 3. score MFMAs
    v4f s[2][2];
#pragma unroll
    for (int si = 0; si < 2; si++)
#pragma unroll
      for (int n = 0; n < 2; n++) s[si][n] = vz;
#pragma unroll
    for (int c = 0; c < 4; c++)
#pragma unroll
      for (int si = 0; si < 2; si++)
#pragma unroll
        for (int n = 0; n < 2; n++)
          s[si][n] = MFMA(ka[si][c], qf[n][c], s[si][n]);

    // 4. exp, write P~ to sP[h][k][i] (stride-80 rows, 4 consecutive i/lane)
#pragma unroll
    for (int si = 0; si < 2; si++)
#pragma unroll
      for (int n = 0; n < 2; n++) {
        const float p0 = exp2f(s[si][n][0] * c2);
        const float p1 = exp2f(s[si][n][1] * c2);
        const float p2 = exp2f(s[si][n][2] * c2);
        const float p3 = exp2f(s[si][n][3] * c2);
        uint2 w;
        w.x = pack2(p0, p1);
        w.y = pack2(p2, p3);
        *(uint2*)(sPh + (n * 16 + l15) * 80 + (si * 16 + q * 4) * 2) = w;
      }
    barrier_lgkm();

    // 5. normalize across heads: thread owns (k=kk, i = 2*ip, 2*ip+1)
    {
      unsigned u[8];
      float lo[8], hi[8], s0 = 0.f, s1 = 0.f;
#pragma unroll
      for (int hh = 0; hh < 8; hh++)
        u[hh] = *(const unsigned*)(sP + hh * 2560 + kk * 80 + ip * 4);
#pragma unroll
      for (int hh = 0; hh < 8; hh++) {
        lo[hh] = __builtin_bit_cast(float, u[hh] << 16);
        hi[hh] = __builtin_bit_cast(float, u[hh] & 0xFFFF0000u);
        s0 += lo[hh];
        s1 += hi[hh];
      }
      const float r0 = __builtin_amdgcn_rcpf(s0);
      const float r1 = __builtin_amdgcn_rcpf(s1);
#pragma unroll
      for (int hh = 0; hh < 8; hh++)
        *(unsigned*)(sP + hh * 2560 + kk * 80 + ip * 4) = pack2(lo[hh] * r0, hi[hh] * r1);
    }
    barrier_lgkm();

    // 6. PV: va from conflict-free sV, pb from sP
    {
      char* sVp = sV + p * 65536 + h * 8192;
      v8bf va[8], pb[2];
#pragma unroll
      for (int t = 0; t < 8; t++)
        va[t] = *(const v8bf*)(sVp + q * 2048 + (t * 16 + l15) * 16);
#pragma unroll
      for (int n = 0; n < 2; n++)
        pb[n] = *(const v8bf*)(sPh + (n * 16 + l15) * 80 + q * 16);
#pragma unroll
      for (int t = 0; t < 8; t++)
#pragma unroll
        for (int n = 0; n < 2; n++)
          cacc[t][n] = MFMA(va[t], pb[n], cacc[t][n]);
    }
  }

  // ---- epilogue: C[dd=128][k=32] -> Hd[b*L + k][h*128 + dd] ----
#pragma unroll
  for (int t = 0; t < 8; t++)
#pragma unroll
    for (int n = 0; n < 2; n++) {
      uint2 w;
      w.x = pack2(cacc[t][n][0], cacc[t][n][1]);
      w.y = pack2(cacc[t][n][2], cacc[t][n][3]);
      char* dst = (char*)Hd +
          (((size_t)(b * L_ + k0 + n * 16 + l15)) * HID + h * DH + t * 16 + q * 4) * 2;
      *(uint2*)dst = w;
    }
}

// ---------------------------------------------------------------------------
// Output projection (pure bf16): out[m][o] = sum Hd[m][k]*Wop[o][k] + bo[o]
// ---------------------------------------------------------------------------
__global__ __launch_bounds__(256, 2)
void outproj_kernel(const __bf16* __restrict__ Hd, const __bf16* __restrict__ Wop,
                    const float* __restrict__ bo, float* __restrict__ out)
{
  __shared__ __bf16 sA[2][64 * 64];
  __shared__ __bf16 sB[2][64 * 64];
  const int tid  = threadIdx.x;
  const int lane = tid & 63;
  const int wid  = tid >> 6;
  const int l15  = lane & 15;
  const int q    = lane >> 4;
  const int mblk = blockIdx.x * 64;
  const int nblk = blockIdx.y * 64;

  const char* Ab = (const char*)Hd  + (size_t)mblk * 2048;
  const char* Bb = (const char*)Wop + (size_t)nblk * 2048;

  auto stage = [&](int p, int c) {
#pragma unroll
    for (int j = 0; j < 2; j++) {
      const int slot = j * 256 + tid;
      const int row = slot >> 3, g = slot & 7;
      gl_lds16(Ab + (size_t)row * 2048 + c * 128 + ((g ^ (row & 7)) << 4),
               &sA[p][(j * 256 + wid * 64) * 8]);
    }
#pragma unroll
    for (int j = 0; j < 2; j++) {
      const int slot = j * 256 + tid;
      const int row = slot >> 3, g = slot & 7;
      gl_lds16(Bb + (size_t)row * 2048 + c * 128 + ((g ^ (row & 7)) << 4),
               &sB[p][(j * 256 + wid * 64) * 8]);
    }
  };

  v4f acc[2][2];
  const v4f vz = {0.f, 0.f, 0.f, 0.f};
#pragma unroll
  for (int i = 0; i < 2; i++)
#pragma unroll
    for (int j = 0; j < 2; j++) acc[i][j] = vz;

  stage(0, 0);
  __syncthreads();
#pragma unroll 1
  for (int c = 0; c < 16; c++) {
    const int p = c & 1;
    if (c + 1 < 16) stage(1 - p, c + 1);
#pragma unroll
    for (int s = 0; s < 2; s++) {
      v8bf a[2], bb[2];
#pragma unroll
      for (int t = 0; t < 2; t++) {
        const int row = (wid & 1) * 32 + t * 16 + l15;
        a[t] = *(const v8bf*)&sA[p][(row << 6) + (((s * 4 + q) ^ (row & 7)) << 3)];
      }
#pragma unroll
      for (int t = 0; t < 2; t++) {
        const int row = (wid >> 1) * 32 + t * 16 + l15;
        bb[t] = *(const v8bf*)&sB[p][(row << 6) + (((s * 4 + q) ^ (row & 7)) << 3)];
      }
#pragma unroll
      for (int tm = 0; tm < 2; tm++)
#pragma unroll
        for (int tn = 0; tn < 2; tn++)
          acc[tm][tn] = MFMA(a[tm], bb[tn], acc[tm][tn]);
    }
    __syncthreads();
  }

#pragma unroll
  for (int tn = 0; tn < 2; tn++) {
    const int n = nblk + (wid >> 1) * 32 + tn * 16 + l15;
    const float bv = bo[n];
#pragma unroll
    for (int tm = 0; tm < 2; tm++)
#pragma unroll
      for (int r = 0; r < 4; r++) {
        const int m = mblk + (wid & 1) * 32 + tm * 16 + q * 4 + r;
        out[(size_t)m * OUTF + n] = acc[tm][tn][r] + bv;
      }
  }
}

// ---------------------------------------------------------------------------
// Workspace layout (bytes):
//   0      Kp   16 MiB  [B*NH][L][DH] bf16
//   16 MiB Qp   16 MiB
//   32 MiB Vpt  16 MiB  [B*NH][DH][L]
//   48 MiB Hd   16 MiB  [B*L][h*128+dd]  (conv X/W area inside, dead by then)
//   64 MiB Wop  512 KiB [O][h*128+dd] bf16
// ---------------------------------------------------------------------------
extern "C" void kernel_launch(void* const* d_in, const int* in_sizes, int n_in,
                              void* d_out, int out_size, void* d_ws, size_t ws_size,
                              hipStream_t stream) {
  const float* KEY   = (const float*)d_in[0];
  const float* VALUE = (const float*)d_in[1];
  const float* QUERY = (const float*)d_in[2];
  const float* W_w   = (const float*)d_in[3];
  const float* W_b   = (const float*)d_in[4];
  const float* Wv_w  = (const float*)d_in[5];
  const float* Wv_b  = (const float*)d_in[6];
  const float* Wo_w  = (const float*)d_in[7];
  const float* Wo_b  = (const float*)d_in[8];
  float* out = (float*)d_out;

  const size_t MB = 1024 * 1024;
  char* ws = (char*)d_ws;
  __bf16* Kp  = (__bf16*)(ws);
  __bf16* Qp  = (__bf16*)(ws + 16 * MB);
  __bf16* Vpt = (__bf16*)(ws + 32 * MB);
  __bf16* Hd  = (__bf16*)(ws + 48 * MB);
  __bf16* Wop = (__bf16*)(ws + 64 * MB);
  // conversion area inside Hd region (dead before fused_attn writes Hd)
  __bf16* Xk  = (__bf16*)(ws + 48 * MB);
  __bf16* Xq  = (__bf16*)(ws + 48 * MB + 4 * MB);
  __bf16* Xv  = (__bf16*)(ws + 48 * MB + 8 * MB);
  __bf16* Wb  = (__bf16*)(ws + 48 * MB + 12 * MB);
  __bf16* Wvb = (__bf16*)(ws + 48 * MB + 12 * MB + 512 * 1024);

  ConvArgs ca;
  ca.src[0] = KEY;   ca.dst[0] = Xk;  ca.n[0] = B_ * L_ * INK;
  ca.src[1] = QUERY; ca.dst[1] = Xq;  ca.n[1] = B_ * L_ * INK;
  ca.src[2] = VALUE; ca.dst[2] = Xv;  ca.n[2] = B_ * L_ * INK;
  ca.src[3] = W_w;   ca.dst[3] = Wb;  ca.n[3] = HID * INK;
  ca.src[4] = Wv_w;  ca.dst[4] = Wvb; ca.n[4] = HID * INK;
  convert_kernel<<<dim3(2048, 5), 256, 0, stream>>>(ca);
  wo_perm_kernel<<<dim3(256), 256, 0, stream>>>(Wo_w, Wop);

  proj_kernel<0><<<dim3(64, 8), 256, 0, stream>>>(Xk, Wb,  W_b,  Kp);
  proj_kernel<0><<<dim3(64, 8), 256, 0, stream>>>(Xq, Wb,  W_b,  Qp);
  proj_kernel<1><<<dim3(64, 8), 256, 0, stream>>>(Xv, Wvb, Wv_b, Vpt);

  fused_attn_kernel<<<dim3(64, B_), 512, 151552, stream>>>(Kp, Qp, Vpt, Hd);

  outproj_kernel<<<dim3(128, 4), 256, 0, stream>>>(Hd, Wop, Wo_b, out);
}